// Round 15
// baseline (710.233 us; speedup 1.0000x reference)
//
#include <hip/hip_runtime.h>

typedef unsigned int u32;
typedef unsigned short u16;
typedef __bf16 bf16x8 __attribute__((ext_vector_type(8)));
typedef float f32x16 __attribute__((ext_vector_type(16)));
typedef float f32x4v __attribute__((ext_vector_type(4)));
typedef u32 u32x4 __attribute__((ext_vector_type(4)));
typedef u32 u32x2 __attribute__((ext_vector_type(2)));

#define BATCH    32768
#define DIN      256
#define UNITS    512
#define BM       64
#define NTHREADS 1024
#define NSTEP    6
#define DT       (1.0f/6.0f)
#define TANH_C   2.885390082f            // 2*log2(e), folded into Kp/Rp/bias
#define SMEM_BYTES (65536 + 65536 + 32768)   // heA + h1L + xkbL1 = 160KB

__device__ __forceinline__ u16 f2bf(float f) {
  return __builtin_bit_cast(u16, (__bf16)f);
}
__device__ __forceinline__ float bf2f(u16 b) {
  return __builtin_bit_cast(float, (u32)b << 16);
}
__device__ __forceinline__ u32 pk2(float a, float b) {
  return (u32)f2bf(a) | ((u32)f2bf(b) << 16);
}
// arg is pre-scaled by 2*log2(e); tanh = 1 - 2/(2^t + 1)
__device__ __forceinline__ float tanh_pre(float t) {
  float a = __builtin_amdgcn_exp2f(fminf(t, 60.f));
  float r = __builtin_amdgcn_rcpf(a + 1.f);
  return __builtin_fmaf(-2.f, r, 1.f);
}

// Pack K (256x512) and R (512x512) f32 row-major into bf16 B-fragment order,
// PRE-SCALED by TANH_C. chunk c = g*512 + n holds rows g*8..g*8+7, col n.
__global__ void pack_weights(const float* __restrict__ Km, const float* __restrict__ Rm,
                             u16* __restrict__ Kp, u16* __restrict__ Rp) {
  int c = blockIdx.x * 256 + threadIdx.x;          // 0 .. 49151
  if (c < 32768) {
    int n = c & 511, g = c >> 9;                   // g < 64
    u32x4 p;
#pragma unroll
    for (int i = 0; i < 4; ++i) {
      u16 lo = f2bf(Rm[(g * 8 + 2 * i) * 512 + n] * TANH_C);
      u16 hh = f2bf(Rm[(g * 8 + 2 * i + 1) * 512 + n] * TANH_C);
      p[i] = (u32)lo | ((u32)hh << 16);
    }
    ((u32x4*)Rp)[c] = p;
  } else {
    int c2 = c - 32768;                            // < 16384
    int n = c2 & 511, g = c2 >> 9;                 // g < 32
    u32x4 p;
#pragma unroll
    for (int i = 0; i < 4; ++i) {
      u16 lo = f2bf(Km[(g * 8 + 2 * i) * 512 + n] * TANH_C);
      u16 hh = f2bf(Km[(g * 8 + 2 * i + 1) * 512 + n] * TANH_C);
      p[i] = (u32)lo | ((u32)hh << 16);
    }
    ((u32x4*)Kp)[c2] = p;
  }
}

__global__ __launch_bounds__(NTHREADS, 4)
void ctrnn_fused(const float* __restrict__ X, const float* __restrict__ H0,
                 const u16* __restrict__ Kp, const u16* __restrict__ Rp,
                 const float* __restrict__ bias, const float* __restrict__ scale,
                 float* __restrict__ out) {
  // heA 64KB: he bf16, A-fragment order with block-XOR swizzle.
  //   Element (row,col), tile t=row>>5, chunk=col>>4 (32r x 16c per 1KB chunk),
  //   block = ((col>>3)&1)*32 + (row&31):
  //     addr = t*32768 + chunk*1024 + ((block ^ (chunk&7))<<4) + (col&7)*2
  //   A-read lane l, k-block kb: addr = t*32768 + kb*1024 + ((l<<4) ^ ((kb&7)<<4))
  //   (bijective per chunk -> conflict-free; scalar access gains ln>>4/hi in the
  //   bank index -> 2-way (free) instead of 4-way).
  // h1L 64KB: f32 h of col-subtile1, [r][tid] per-thread-private slots.
  // xkbL1 32KB: packed-bf16 xkb of col-subtile1, u32 [i][tid].
  extern __shared__ char smem[];
  char* heA  = smem;
  float* h1L = (float*)(smem + 65536);
  u32* xkbL1 = (u32*)(smem + 131072);

  const int tid  = threadIdx.x;
  const int lane = tid & 63;
  const int wv   = tid >> 6;
  const int wm   = wv >> 3, wn = wv & 7;   // 2 x 8 grid: row-tile x col-pair
  const int ln   = lane & 31, hi = lane >> 5;
  const long r0  = (long)blockIdx.x * BM;

  const int jc0  = wn * 64 + ln;           // col-subtile 0
  const int jc1  = jc0 + 32;               // col-subtile 1
  const int aoff = lane << 4;
  const int Abase = wm * 32768;            // he A-frag base (own row-tile)
  const int AbaseX = wm * 16384;           // x A-frag base
  // scalar-he base (own rows mm+hi*4, col jc0): addr = cb0 + ((mm<<4) ^ U0)
  const int chunk0 = wn * 4 + (ln >> 4);
  const int cb0 = wm * 32768 + chunk0 * 1024 + (((ln >> 3) & 1) << 9) + ((ln & 7) << 1);
  const int U0  = ((hi << 2) ^ (chunk0 & 7)) << 4;
  const int U1  = U0 ^ 32;                 // col jc1: chunk+2 -> s^2

  // stage x tile -> swizzled A-fragment order, tile stride 16384
  {
    const f32x4v* X4 = (const f32x4v*)(X + r0 * DIN);
#pragma unroll
    for (int i = 0; i < 4; ++i) {
      int flat = i * NTHREADS + tid;       // 0..4095 float4-chunks
      int m = flat >> 6, c4 = flat & 63;   // row m, cols c4*4..+3
      f32x4v v = X4[m * 64 + c4];
      u32x2 p;
      p.x = pk2(v.x, v.y);
      p.y = pk2(v.z, v.w);
      int chunk = c4 >> 2;
      int block = ((c4 >> 1) & 1) * 32 + (m & 31);
      int addr = (m >> 5) * 16384 + chunk * 1024
               + ((block ^ (chunk & 7)) << 4) + (c4 & 1) * 8;
      *(u32x2*)(heA + addr) = p;
    }
  }

  const float scl0 = scale[jc0], scl1 = scale[jc1];

  // load h: col-subtile0 -> regs, col-subtile1 -> h1L (same rows: own row-tile)
  float h0[16];
#pragma unroll
  for (int r = 0; r < 16; ++r) {
    int m = (r & 3) + ((r >> 2) << 3) + hi * 4 + wm * 32;
    h0[r] = H0[(r0 + m) * UNITS + jc0];
    h1L[r * NTHREADS + tid] = H0[(r0 + m) * UNITS + jc1];
  }

  __syncthreads();

  // ---- prologue: xkb = TANH_C*(x@K + b); per-wave own row-tile A-frags ----
  {
    f32x16 pre0, pre1;
    {
      float b0 = bias[jc0] * TANH_C, b1 = bias[jc1] * TANH_C;
#pragma unroll
      for (int r = 0; r < 16; ++r) { pre0[r] = b0; pre1[r] = b1; }
    }
    const u32x4* Kp4 = (const u32x4*)Kp;
#pragma unroll 2
    for (int kb = 0; kb < 16; ++kb) {
      bf16x8 a = __builtin_bit_cast(bf16x8,
          *(const u32x4*)(heA + AbaseX + kb * 1024 + (aoff ^ ((kb & 7) << 4))));
      bf16x8 b0 = __builtin_bit_cast(bf16x8, Kp4[(kb * 2 + hi) * 512 + jc0]);
      bf16x8 b1 = __builtin_bit_cast(bf16x8, Kp4[(kb * 2 + hi) * 512 + jc1]);
      pre0 = __builtin_amdgcn_mfma_f32_32x32x16_bf16(a, b0, pre0, 0, 0, 0);
      pre1 = __builtin_amdgcn_mfma_f32_32x32x16_bf16(a, b1, pre1, 0, 0, 0);
    }
    u32 xkbP0t[8];
#pragma unroll
    for (int i = 0; i < 8; ++i) {
      xkbP0t[i] = pk2(pre0[2 * i], pre0[2 * i + 1]);
      xkbL1[i * NTHREADS + tid] = pk2(pre1[2 * i], pre1[2 * i + 1]);
    }
    __syncthreads();   // prologue x-reads + xkbL1 writes complete; heA -> he buffer

    // write he_1 = bf16(h), both col-subtiles
#pragma unroll
    for (int r = 0; r < 16; ++r) {
      int mm = (r & 3) + ((r >> 2) << 3);
      *(u16*)(heA + cb0 + ((mm << 4) ^ U0))        = f2bf(h0[r]);
      *(u16*)(heA + cb0 + 2048 + ((mm << 4) ^ U1)) = f2bf(h1L[r * NTHREADS + tid]);
    }
    __syncthreads();

    const u32x4* Rp4 = (const u32x4*)Rp;
    u32 accP0[8], accP1[8];
    u32 xkbP0[8];
#pragma unroll
    for (int i = 0; i < 8; ++i) xkbP0[i] = xkbP0t[i];

#pragma unroll 1
    for (int it = 0; it < NSTEP * 4; ++it) {
      const int ev = it & 3;
      const float wk = (ev == 1 || ev == 2) ? 2.f : 1.f;
      const float ce = (ev < 2) ? (DT * 0.5f) : DT;
      const bool ev0 = (ev == 0), ev3 = (ev == 3);
      const bool last = (it == NSTEP * 4 - 1);

      // pre init: subtile0 from regs, subtile1 from xkbL1
      f32x16 p0, p1;
#pragma unroll
      for (int i = 0; i < 8; ++i) {
        u32 q0 = xkbP0[i];
        u32 q1 = xkbL1[i * NTHREADS + tid];
        p0[2 * i]     = bf2f((u16)(q0 & 0xffffu));
        p0[2 * i + 1] = bf2f((u16)(q0 >> 16));
        p1[2 * i]     = bf2f((u16)(q1 & 0xffffu));
        p1[2 * i + 1] = bf2f((u16)(q1 >> 16));
      }
      // K-loop: ONE A-frag read (own row-tile), two B-frags (col-subtiles)
#pragma unroll 2
      for (int kb = 0; kb < 32; ++kb) {
        bf16x8 a = __builtin_bit_cast(bf16x8,
            *(const u32x4*)(heA + Abase + kb * 1024 + (aoff ^ ((kb & 7) << 4))));
        bf16x8 b0 = __builtin_bit_cast(bf16x8, Rp4[(kb * 2 + hi) * 512 + jc0]);
        bf16x8 b1 = __builtin_bit_cast(bf16x8, Rp4[(kb * 2 + hi) * 512 + jc1]);
        p0 = __builtin_amdgcn_mfma_f32_32x32x16_bf16(a, b0, p0, 0, 0, 0);
        p1 = __builtin_amdgcn_mfma_f32_32x32x16_bf16(a, b1, p1, 0, 0, 0);
      }

      // epilogue subtile0 (h in regs); stash k into p0
#pragma unroll
      for (int rp = 0; rp < 8; ++rp) {
        int mmA = ((2 * rp) & 3) + (((2 * rp) >> 2) << 3);
        int mmB = ((2 * rp + 1) & 3) + (((2 * rp + 1) >> 2) << 3);
        float he0 = bf2f(*(const u16*)(heA + cb0 + ((mmA << 4) ^ U0)));
        float he1 = bf2f(*(const u16*)(heA + cb0 + ((mmB << 4) ^ U0)));
        float k0 = __builtin_fmaf(scl0, tanh_pre(p0[2 * rp]),     -he0);
        float k1 = __builtin_fmaf(scl0, tanh_pre(p0[2 * rp + 1]), -he1);
        float a0 = (ev0 ? 0.f : bf2f((u16)(accP0[rp] & 0xffffu))) + wk * k0;
        float a1 = (ev0 ? 0.f : bf2f((u16)(accP0[rp] >> 16)))     + wk * k1;
        if (ev3) {
          h0[2 * rp]     += (DT / 6.f) * a0;
          h0[2 * rp + 1] += (DT / 6.f) * a1;
        } else {
          accP0[rp] = pk2(a0, a1);
        }
        p0[2 * rp] = k0; p0[2 * rp + 1] = k1;
      }
      // epilogue subtile1 (h in h1L); stash k into p1
#pragma unroll
      for (int rp = 0; rp < 8; ++rp) {
        int mmA = ((2 * rp) & 3) + (((2 * rp) >> 2) << 3);
        int mmB = ((2 * rp + 1) & 3) + (((2 * rp + 1) >> 2) << 3);
        float he0 = bf2f(*(const u16*)(heA + cb0 + 2048 + ((mmA << 4) ^ U1)));
        float he1 = bf2f(*(const u16*)(heA + cb0 + 2048 + ((mmB << 4) ^ U1)));
        float k0 = __builtin_fmaf(scl1, tanh_pre(p1[2 * rp]),     -he0);
        float k1 = __builtin_fmaf(scl1, tanh_pre(p1[2 * rp + 1]), -he1);
        float a0 = (ev0 ? 0.f : bf2f((u16)(accP1[rp] & 0xffffu))) + wk * k0;
        float a1 = (ev0 ? 0.f : bf2f((u16)(accP1[rp] >> 16)))     + wk * k1;
        if (ev3) {
          float hv0 = h1L[(2 * rp) * NTHREADS + tid]     + (DT / 6.f) * a0;
          float hv1 = h1L[(2 * rp + 1) * NTHREADS + tid] + (DT / 6.f) * a1;
          h1L[(2 * rp) * NTHREADS + tid]     = hv0;
          h1L[(2 * rp + 1) * NTHREADS + tid] = hv1;
        } else {
          accP1[rp] = pk2(a0, a1);
        }
        p1[2 * rp] = k0; p1[2 * rp + 1] = k1;
      }
      __syncthreads();   // all heA reads (A-frags + he_i) of this eval complete

      if (!last) {
        // write he_next = (ev3) ? h : h + ce*k  (k stashed in p0/p1)
#pragma unroll
        for (int r = 0; r < 16; ++r) {
          int mm = (r & 3) + ((r >> 2) << 3);
          float v0 = ev3 ? h0[r] : h0[r] + ce * p0[r];
          *(u16*)(heA + cb0 + ((mm << 4) ^ U0)) = f2bf(v0);
          float hv = h1L[r * NTHREADS + tid];
          float v1 = ev3 ? hv : hv + ce * p1[r];
          *(u16*)(heA + cb0 + 2048 + ((mm << 4) ^ U1)) = f2bf(v1);
        }
        __syncthreads();   // he_{i+1} visible
      }
    }
  }

  // store final h: subtile0 from regs, subtile1 from h1L
#pragma unroll
  for (int r = 0; r < 16; ++r) {
    int m = (r & 3) + ((r >> 2) << 3) + hi * 4 + wm * 32;
    out[(r0 + m) * UNITS + jc0] = h0[r];
    out[(r0 + m) * UNITS + jc1] = h1L[r * NTHREADS + tid];
  }
}

extern "C" void kernel_launch(void* const* d_in, const int* in_sizes, int n_in,
                              void* d_out, int out_size, void* d_ws, size_t ws_size,
                              hipStream_t stream) {
  const float* X     = (const float*)d_in[0];
  const float* H0    = (const float*)d_in[1];
  const float* Km    = (const float*)d_in[2];
  const float* Rm    = (const float*)d_in[3];
  const float* bias  = (const float*)d_in[4];
  const float* scale = (const float*)d_in[5];
  float* out = (float*)d_out;

  u16* Rp = (u16*)d_ws;                  // 512*512 bf16 = 512KB
  u16* Kp = Rp + UNITS * UNITS;          // 256*512 bf16 = 256KB

  (void)hipFuncSetAttribute((const void*)ctrnn_fused,
                            hipFuncAttributeMaxDynamicSharedMemorySize, SMEM_BYTES);

  pack_weights<<<192, 256, 0, stream>>>(Km, Rm, Kp, Rp);
  ctrnn_fused<<<BATCH / BM, NTHREADS, SMEM_BYTES, stream>>>(X, H0, Kp, Rp, bias, scale, out);
}

// Round 16
// 666.352 us; speedup vs baseline: 1.0659x; 1.0659x over previous
//
#include <hip/hip_runtime.h>

typedef unsigned int u32;
typedef unsigned short u16;
typedef __bf16 bf16x8 __attribute__((ext_vector_type(8)));
typedef float f32x16 __attribute__((ext_vector_type(16)));
typedef float f32x4v __attribute__((ext_vector_type(4)));
typedef u32 u32x4 __attribute__((ext_vector_type(4)));
typedef u32 u32x2 __attribute__((ext_vector_type(2)));

#define BATCH    32768
#define DIN      256
#define UNITS    512
#define BM       32
#define NTHREADS 512
#define NSTEP    6
#define DT       (1.0f/6.0f)
#define TANH_C   2.885390082f            // 2*log2(e), folded into Kp/Rp/bias
#define SMEM_BYTES (32768 + 32768 + 16384)   // heA + h1L + xkbL1 = 80KB -> 2 blocks/CU

__device__ __forceinline__ u16 f2bf(float f) {
  return __builtin_bit_cast(u16, (__bf16)f);
}
__device__ __forceinline__ float bf2f(u16 b) {
  return __builtin_bit_cast(float, (u32)b << 16);
}
__device__ __forceinline__ u32 pk2(float a, float b) {
  return (u32)f2bf(a) | ((u32)f2bf(b) << 16);
}
// arg is pre-scaled by 2*log2(e); tanh = 1 - 2/(2^t + 1)
__device__ __forceinline__ float tanh_pre(float t) {
  float a = __builtin_amdgcn_exp2f(fminf(t, 60.f));
  float r = __builtin_amdgcn_rcpf(a + 1.f);
  return __builtin_fmaf(-2.f, r, 1.f);
}

// Pack K (256x512) and R (512x512) f32 row-major into bf16 B-fragment order,
// PRE-SCALED by TANH_C. chunk c = g*512 + n holds rows g*8..g*8+7, col n.
__global__ void pack_weights(const float* __restrict__ Km, const float* __restrict__ Rm,
                             u16* __restrict__ Kp, u16* __restrict__ Rp) {
  int c = blockIdx.x * 256 + threadIdx.x;          // 0 .. 49151
  if (c < 32768) {
    int n = c & 511, g = c >> 9;                   // g < 64
    u32x4 p;
#pragma unroll
    for (int i = 0; i < 4; ++i) {
      u16 lo = f2bf(Rm[(g * 8 + 2 * i) * 512 + n] * TANH_C);
      u16 hh = f2bf(Rm[(g * 8 + 2 * i + 1) * 512 + n] * TANH_C);
      p[i] = (u32)lo | ((u32)hh << 16);
    }
    ((u32x4*)Rp)[c] = p;
  } else {
    int c2 = c - 32768;                            // < 16384
    int n = c2 & 511, g = c2 >> 9;                 // g < 32
    u32x4 p;
#pragma unroll
    for (int i = 0; i < 4; ++i) {
      u16 lo = f2bf(Km[(g * 8 + 2 * i) * 512 + n] * TANH_C);
      u16 hh = f2bf(Km[(g * 8 + 2 * i + 1) * 512 + n] * TANH_C);
      p[i] = (u32)lo | ((u32)hh << 16);
    }
    ((u32x4*)Kp)[c2] = p;
  }
}

__global__ __launch_bounds__(NTHREADS, 4)
void ctrnn_fused(const float* __restrict__ X, const float* __restrict__ H0,
                 const u16* __restrict__ Kp, const u16* __restrict__ Rp,
                 const float* __restrict__ bias, const float* __restrict__ scale,
                 float* __restrict__ out) {
  // heA 32KB: he bf16 [32 rows][512 cols], A-fragment order + block-XOR swizzle.
  //   Element (row,col), chunk=col>>4 (32r x 16c per 1KB chunk),
  //   block = ((col>>3)&1)*32 + (row&31):
  //     addr = chunk*1024 + ((block ^ (chunk&7))<<4) + (col&7)*2
  //   A-read lane l, k-block kb: addr = kb*1024 + ((l<<4) ^ ((kb&7)<<4))
  //   (conflict-free; scalar he access ~2-way).
  //   Prologue stages x the same way (16 chunks = 16KB region).
  // h1L 32KB: f32 h of col-subtile1, [r][tid] per-thread-private slots.
  // xkbL1 16KB: packed-bf16 xkb of col-subtile1, u32 [i][tid].
  extern __shared__ char smem[];
  char* heA  = smem;
  float* h1L = (float*)(smem + 32768);
  u32* xkbL1 = (u32*)(smem + 65536);

  const int tid  = threadIdx.x;
  const int lane = tid & 63;
  const int wv   = tid >> 6;               // 0..7 — wave owns cols [wv*64, wv*64+64)
  const int ln   = lane & 31, hi = lane >> 5;
  const long r0  = (long)blockIdx.x * BM;

  const int jc0  = wv * 64 + ln;           // col-subtile 0
  const int jc1  = jc0 + 32;               // col-subtile 1
  const int aoff = lane << 4;
  // scalar-he base (rows mm+hi*4, col jc0): addr = cb0 + ((mm<<4) ^ U0)
  const int chunk0 = wv * 4 + (ln >> 4);
  const int cb0 = chunk0 * 1024 + (((ln >> 3) & 1) << 9) + ((ln & 7) << 1);
  const int U0  = ((hi << 2) ^ (chunk0 & 7)) << 4;
  const int U1  = U0 ^ 32;                 // col jc1: chunk+2 -> swz^2

  // stage x tile -> swizzled A-fragment order (16 chunks, 16KB)
  {
    const f32x4v* X4 = (const f32x4v*)(X + r0 * DIN);
#pragma unroll
    for (int i = 0; i < 4; ++i) {
      int flat = i * NTHREADS + tid;       // 0..2047 float4-chunks
      int m = flat >> 6, c4 = flat & 63;   // row m (0..31), cols c4*4..+3
      f32x4v v = X4[m * 64 + c4];
      u32x2 p;
      p.x = pk2(v.x, v.y);
      p.y = pk2(v.z, v.w);
      int chunk = c4 >> 2;
      int block = ((c4 >> 1) & 1) * 32 + (m & 31);
      int addr = chunk * 1024 + ((block ^ (chunk & 7)) << 4) + (c4 & 1) * 8;
      *(u32x2*)(heA + addr) = p;
    }
  }

  const float scl0 = scale[jc0], scl1 = scale[jc1];

  // load h: col-subtile0 -> regs, col-subtile1 -> h1L
  float h0[16];
#pragma unroll
  for (int r = 0; r < 16; ++r) {
    int m = (r & 3) + ((r >> 2) << 3) + hi * 4;
    h0[r] = H0[(r0 + m) * UNITS + jc0];
    h1L[r * NTHREADS + tid] = H0[(r0 + m) * UNITS + jc1];
  }

  __syncthreads();

  // ---- prologue: xkb = TANH_C*(x@K + b) ----
  {
    f32x16 pre0, pre1;
    {
      float b0 = bias[jc0] * TANH_C, b1 = bias[jc1] * TANH_C;
#pragma unroll
      for (int r = 0; r < 16; ++r) { pre0[r] = b0; pre1[r] = b1; }
    }
    const u32x4* Kp4 = (const u32x4*)Kp;
#pragma unroll 2
    for (int kb = 0; kb < 16; ++kb) {
      bf16x8 a = __builtin_bit_cast(bf16x8,
          *(const u32x4*)(heA + kb * 1024 + (aoff ^ ((kb & 7) << 4))));
      bf16x8 b0 = __builtin_bit_cast(bf16x8, Kp4[(kb * 2 + hi) * 512 + jc0]);
      bf16x8 b1 = __builtin_bit_cast(bf16x8, Kp4[(kb * 2 + hi) * 512 + jc1]);
      pre0 = __builtin_amdgcn_mfma_f32_32x32x16_bf16(a, b0, pre0, 0, 0, 0);
      pre1 = __builtin_amdgcn_mfma_f32_32x32x16_bf16(a, b1, pre1, 0, 0, 0);
    }
    u32 xkbP0t[8];
#pragma unroll
    for (int i = 0; i < 8; ++i) {
      xkbP0t[i] = pk2(pre0[2 * i], pre0[2 * i + 1]);
      xkbL1[i * NTHREADS + tid] = pk2(pre1[2 * i], pre1[2 * i + 1]);
    }
    __syncthreads();   // prologue x-reads + xkbL1 writes complete; heA -> he buffer

    // write he_1 = bf16(h), both col-subtiles
#pragma unroll
    for (int r = 0; r < 16; ++r) {
      int mm = (r & 3) + ((r >> 2) << 3);
      *(u16*)(heA + cb0 + ((mm << 4) ^ U0))        = f2bf(h0[r]);
      *(u16*)(heA + cb0 + 2048 + ((mm << 4) ^ U1)) = f2bf(h1L[r * NTHREADS + tid]);
    }
    __syncthreads();

    const u32x4* Rp4 = (const u32x4*)Rp;
    u32 accP0[8], accP1[8];
    u32 xkbP0[8];
#pragma unroll
    for (int i = 0; i < 8; ++i) xkbP0[i] = xkbP0t[i];

#pragma unroll 1
    for (int it = 0; it < NSTEP * 4; ++it) {
      const int ev = it & 3;
      const float wk = (ev == 1 || ev == 2) ? 2.f : 1.f;
      const float ce = (ev < 2) ? (DT * 0.5f) : DT;
      const bool ev0 = (ev == 0), ev3 = (ev == 3);
      const bool last = (it == NSTEP * 4 - 1);

      // pre init: subtile0 from regs, subtile1 from xkbL1
      f32x16 p0, p1;
#pragma unroll
      for (int i = 0; i < 8; ++i) {
        u32 q0 = xkbP0[i];
        u32 q1 = xkbL1[i * NTHREADS + tid];
        p0[2 * i]     = bf2f((u16)(q0 & 0xffffu));
        p0[2 * i + 1] = bf2f((u16)(q0 >> 16));
        p1[2 * i]     = bf2f((u16)(q1 & 0xffffu));
        p1[2 * i + 1] = bf2f((u16)(q1 >> 16));
      }
      // K-loop: ONE A-frag read, two B-frags (col-subtiles)
#pragma unroll 2
      for (int kb = 0; kb < 32; ++kb) {
        bf16x8 a = __builtin_bit_cast(bf16x8,
            *(const u32x4*)(heA + kb * 1024 + (aoff ^ ((kb & 7) << 4))));
        bf16x8 b0 = __builtin_bit_cast(bf16x8, Rp4[(kb * 2 + hi) * 512 + jc0]);
        bf16x8 b1 = __builtin_bit_cast(bf16x8, Rp4[(kb * 2 + hi) * 512 + jc1]);
        p0 = __builtin_amdgcn_mfma_f32_32x32x16_bf16(a, b0, p0, 0, 0, 0);
        p1 = __builtin_amdgcn_mfma_f32_32x32x16_bf16(a, b1, p1, 0, 0, 0);
      }

      // epilogue subtile0 (h in regs); stash k into p0
#pragma unroll
      for (int rp = 0; rp < 8; ++rp) {
        int mmA = ((2 * rp) & 3) + (((2 * rp) >> 2) << 3);
        int mmB = ((2 * rp + 1) & 3) + (((2 * rp + 1) >> 2) << 3);
        float he0 = bf2f(*(const u16*)(heA + cb0 + ((mmA << 4) ^ U0)));
        float he1 = bf2f(*(const u16*)(heA + cb0 + ((mmB << 4) ^ U0)));
        float k0 = __builtin_fmaf(scl0, tanh_pre(p0[2 * rp]),     -he0);
        float k1 = __builtin_fmaf(scl0, tanh_pre(p0[2 * rp + 1]), -he1);
        float a0 = (ev0 ? 0.f : bf2f((u16)(accP0[rp] & 0xffffu))) + wk * k0;
        float a1 = (ev0 ? 0.f : bf2f((u16)(accP0[rp] >> 16)))     + wk * k1;
        if (ev3) {
          h0[2 * rp]     += (DT / 6.f) * a0;
          h0[2 * rp + 1] += (DT / 6.f) * a1;
        } else {
          accP0[rp] = pk2(a0, a1);
        }
        p0[2 * rp] = k0; p0[2 * rp + 1] = k1;
      }
      // epilogue subtile1 (h in h1L); stash k into p1
#pragma unroll
      for (int rp = 0; rp < 8; ++rp) {
        int mmA = ((2 * rp) & 3) + (((2 * rp) >> 2) << 3);
        int mmB = ((2 * rp + 1) & 3) + (((2 * rp + 1) >> 2) << 3);
        float he0 = bf2f(*(const u16*)(heA + cb0 + 2048 + ((mmA << 4) ^ U1)));
        float he1 = bf2f(*(const u16*)(heA + cb0 + 2048 + ((mmB << 4) ^ U1)));
        float k0 = __builtin_fmaf(scl1, tanh_pre(p1[2 * rp]),     -he0);
        float k1 = __builtin_fmaf(scl1, tanh_pre(p1[2 * rp + 1]), -he1);
        float a0 = (ev0 ? 0.f : bf2f((u16)(accP1[rp] & 0xffffu))) + wk * k0;
        float a1 = (ev0 ? 0.f : bf2f((u16)(accP1[rp] >> 16)))     + wk * k1;
        if (ev3) {
          float hv0 = h1L[(2 * rp) * NTHREADS + tid]     + (DT / 6.f) * a0;
          float hv1 = h1L[(2 * rp + 1) * NTHREADS + tid] + (DT / 6.f) * a1;
          h1L[(2 * rp) * NTHREADS + tid]     = hv0;
          h1L[(2 * rp + 1) * NTHREADS + tid] = hv1;
        } else {
          accP1[rp] = pk2(a0, a1);
        }
        p1[2 * rp] = k0; p1[2 * rp + 1] = k1;
      }
      __syncthreads();   // all heA reads (A-frags + he_i) of this eval complete

      if (!last) {
        // write he_next = (ev3) ? h : h + ce*k  (k stashed in p0/p1)
#pragma unroll
        for (int r = 0; r < 16; ++r) {
          int mm = (r & 3) + ((r >> 2) << 3);
          float v0 = ev3 ? h0[r] : h0[r] + ce * p0[r];
          *(u16*)(heA + cb0 + ((mm << 4) ^ U0)) = f2bf(v0);
          float hv = h1L[r * NTHREADS + tid];
          float v1 = ev3 ? hv : hv + ce * p1[r];
          *(u16*)(heA + cb0 + 2048 + ((mm << 4) ^ U1)) = f2bf(v1);
        }
        __syncthreads();   // he_{i+1} visible
      }
    }
  }

  // store final h: subtile0 from regs, subtile1 from h1L
#pragma unroll
  for (int r = 0; r < 16; ++r) {
    int m = (r & 3) + ((r >> 2) << 3) + hi * 4;
    out[(r0 + m) * UNITS + jc0] = h0[r];
    out[(r0 + m) * UNITS + jc1] = h1L[r * NTHREADS + tid];
  }
}

extern "C" void kernel_launch(void* const* d_in, const int* in_sizes, int n_in,
                              void* d_out, int out_size, void* d_ws, size_t ws_size,
                              hipStream_t stream) {
  const float* X     = (const float*)d_in[0];
  const float* H0    = (const float*)d_in[1];
  const float* Km    = (const float*)d_in[2];
  const float* Rm    = (const float*)d_in[3];
  const float* bias  = (const float*)d_in[4];
  const float* scale = (const float*)d_in[5];
  float* out = (float*)d_out;

  u16* Rp = (u16*)d_ws;                  // 512*512 bf16 = 512KB
  u16* Kp = Rp + UNITS * UNITS;          // 256*512 bf16 = 256KB

  (void)hipFuncSetAttribute((const void*)ctrnn_fused,
                            hipFuncAttributeMaxDynamicSharedMemorySize, SMEM_BYTES);

  pack_weights<<<192, 256, 0, stream>>>(Km, Rm, Kp, Rp);
  ctrnn_fused<<<BATCH / BM, NTHREADS, SMEM_BYTES, stream>>>(X, H0, Kp, Rp, bias, scale, out);
}

// Round 17
// 625.519 us; speedup vs baseline: 1.1354x; 1.0653x over previous
//
#include <hip/hip_runtime.h>

typedef unsigned int u32;
typedef unsigned short u16;
typedef __bf16 bf16x8 __attribute__((ext_vector_type(8)));
typedef float f32x16 __attribute__((ext_vector_type(16)));
typedef float f32x4v __attribute__((ext_vector_type(4)));
typedef u32 u32x4 __attribute__((ext_vector_type(4)));
typedef u32 u32x2 __attribute__((ext_vector_type(2)));

#define BATCH    32768
#define DIN      256
#define UNITS    512
#define BM       32
#define NTHREADS 512
#define NSTEP    6
#define DT       (1.0f/6.0f)
#define TANH_C   2.885390082f            // 2*log2(e), folded into Kp/Rp/bias
#define SMEM_BYTES (32768 + 32768 + 16384)   // heA + h1L + xkbL1 = 80KB -> 2 blocks/CU

__device__ __forceinline__ u16 f2bf(float f) {
  return __builtin_bit_cast(u16, (__bf16)f);
}
__device__ __forceinline__ float bf2f(u16 b) {
  return __builtin_bit_cast(float, (u32)b << 16);
}
__device__ __forceinline__ u32 pk2(float a, float b) {
  return (u32)f2bf(a) | ((u32)f2bf(b) << 16);
}
// arg pre-scaled by 2*log2(e); tanh = 1 - 2/(2^t + 1).
// No clamp needed: t->+inf => a=inf, r=0, result 1; t->-inf => a=0, r=1, result -1.
__device__ __forceinline__ float tanh_pre(float t) {
  float a = __builtin_amdgcn_exp2f(t);
  float r = __builtin_amdgcn_rcpf(a + 1.f);
  return __builtin_fmaf(-2.f, r, 1.f);
}

// Pack K (256x512) and R (512x512) f32 row-major into bf16 B-fragment order,
// PRE-SCALED by TANH_C. chunk c = g*512 + n holds rows g*8..g*8+7, col n.
__global__ void pack_weights(const float* __restrict__ Km, const float* __restrict__ Rm,
                             u16* __restrict__ Kp, u16* __restrict__ Rp) {
  int c = blockIdx.x * 256 + threadIdx.x;          // 0 .. 49151
  if (c < 32768) {
    int n = c & 511, g = c >> 9;                   // g < 64
    u32x4 p;
#pragma unroll
    for (int i = 0; i < 4; ++i) {
      u16 lo = f2bf(Rm[(g * 8 + 2 * i) * 512 + n] * TANH_C);
      u16 hh = f2bf(Rm[(g * 8 + 2 * i + 1) * 512 + n] * TANH_C);
      p[i] = (u32)lo | ((u32)hh << 16);
    }
    ((u32x4*)Rp)[c] = p;
  } else {
    int c2 = c - 32768;                            // < 16384
    int n = c2 & 511, g = c2 >> 9;                 // g < 32
    u32x4 p;
#pragma unroll
    for (int i = 0; i < 4; ++i) {
      u16 lo = f2bf(Km[(g * 8 + 2 * i) * 512 + n] * TANH_C);
      u16 hh = f2bf(Km[(g * 8 + 2 * i + 1) * 512 + n] * TANH_C);
      p[i] = (u32)lo | ((u32)hh << 16);
    }
    ((u32x4*)Kp)[c2] = p;
  }
}

__global__ __launch_bounds__(NTHREADS, 4)
void ctrnn_fused(const float* __restrict__ X, const float* __restrict__ H0,
                 const u16* __restrict__ Kp, const u16* __restrict__ Rp,
                 const float* __restrict__ bias, const float* __restrict__ scale,
                 float* __restrict__ out) {
  // heA 32KB: he bf16 [32 rows][512 cols], A-fragment order + block-XOR swizzle.
  //   addr(row,col) = (col>>4)*1024 + (((((col>>3)&1)*32+(row&31)) ^ ((col>>4)&7))<<4) + (col&7)*2
  //   A-read lane l, k-block kb: addr = kb*1024 + ((l<<4) ^ ((kb&7)<<4))  (conflict-free).
  // h1L 32KB: f32 h of col-subtile1, [r][tid] per-thread-private slots.
  // xkbL1 16KB: packed-bf16 xkb of col-subtile1, u32 [i][tid].
  extern __shared__ char smem[];
  char* heA  = smem;
  float* h1L = (float*)(smem + 32768);
  u32* xkbL1 = (u32*)(smem + 65536);

  const int tid  = threadIdx.x;
  const int lane = tid & 63;
  const int wv   = tid >> 6;               // 0..7 — wave owns cols [wv*64, wv*64+64)
  const int ln   = lane & 31, hi = lane >> 5;
  const long r0  = (long)blockIdx.x * BM;

  const int jc0  = wv * 64 + ln;           // col-subtile 0
  const int jc1  = jc0 + 32;               // col-subtile 1
  const int aoff = lane << 4;
  // scalar-he base (rows mm+hi*4, col jc0): addr = cb0 + ((mm<<4) ^ U0)
  const int chunk0 = wv * 4 + (ln >> 4);
  const int cb0 = chunk0 * 1024 + (((ln >> 3) & 1) << 9) + ((ln & 7) << 1);
  const int U0  = ((hi << 2) ^ (chunk0 & 7)) << 4;
  const int U1  = U0 ^ 32;                 // col jc1: chunk+2 -> swz^2

  // stage x tile -> swizzled A-fragment order (16 chunks, 16KB)
  {
    const f32x4v* X4 = (const f32x4v*)(X + r0 * DIN);
#pragma unroll
    for (int i = 0; i < 4; ++i) {
      int flat = i * NTHREADS + tid;       // 0..2047 float4-chunks
      int m = flat >> 6, c4 = flat & 63;   // row m (0..31), cols c4*4..+3
      f32x4v v = X4[m * 64 + c4];
      u32x2 p;
      p.x = pk2(v.x, v.y);
      p.y = pk2(v.z, v.w);
      int chunk = c4 >> 2;
      int block = ((c4 >> 1) & 1) * 32 + (m & 31);
      int addr = chunk * 1024 + ((block ^ (chunk & 7)) << 4) + (c4 & 1) * 8;
      *(u32x2*)(heA + addr) = p;
    }
  }

  const float scl0 = scale[jc0], scl1 = scale[jc1];

  // load h: col-subtile0 -> regs, col-subtile1 -> h1L
  float h0[16];
#pragma unroll
  for (int r = 0; r < 16; ++r) {
    int m = (r & 3) + ((r >> 2) << 3) + hi * 4;
    h0[r] = H0[(r0 + m) * UNITS + jc0];
    h1L[r * NTHREADS + tid] = H0[(r0 + m) * UNITS + jc1];
  }

  __syncthreads();

  // ---- prologue: xkb = TANH_C*(x@K + b) ----
  {
    f32x16 pre0, pre1;
    {
      float b0 = bias[jc0] * TANH_C, b1 = bias[jc1] * TANH_C;
#pragma unroll
      for (int r = 0; r < 16; ++r) { pre0[r] = b0; pre1[r] = b1; }
    }
    const u32x4* Kp4 = (const u32x4*)Kp;
#pragma unroll 2
    for (int kb = 0; kb < 16; ++kb) {
      bf16x8 a = __builtin_bit_cast(bf16x8,
          *(const u32x4*)(heA + kb * 1024 + (aoff ^ ((kb & 7) << 4))));
      bf16x8 b0 = __builtin_bit_cast(bf16x8, Kp4[(kb * 2 + hi) * 512 + jc0]);
      bf16x8 b1 = __builtin_bit_cast(bf16x8, Kp4[(kb * 2 + hi) * 512 + jc1]);
      pre0 = __builtin_amdgcn_mfma_f32_32x32x16_bf16(a, b0, pre0, 0, 0, 0);
      pre1 = __builtin_amdgcn_mfma_f32_32x32x16_bf16(a, b1, pre1, 0, 0, 0);
    }
    u32 xkbP0t[8];
#pragma unroll
    for (int i = 0; i < 8; ++i) {
      xkbP0t[i] = pk2(pre0[2 * i], pre0[2 * i + 1]);
      xkbL1[i * NTHREADS + tid] = pk2(pre1[2 * i], pre1[2 * i + 1]);
    }
    __syncthreads();   // prologue x-reads + xkbL1 writes complete; heA -> he buffer

    // write he_1 = bf16(h), both col-subtiles
#pragma unroll
    for (int r = 0; r < 16; ++r) {
      int mm = (r & 3) + ((r >> 2) << 3);
      *(u16*)(heA + cb0 + ((mm << 4) ^ U0))        = f2bf(h0[r]);
      *(u16*)(heA + cb0 + 2048 + ((mm << 4) ^ U1)) = f2bf(h1L[r * NTHREADS + tid]);
    }
    __syncthreads();

    const u32x4* Rp4 = (const u32x4*)Rp;
    float acc0[16], acc1[16];              // f32 RK4 accumulators (no pack/unpack)
    u32 xkbP0[8];
#pragma unroll
    for (int i = 0; i < 8; ++i) xkbP0[i] = xkbP0t[i];

#pragma unroll 1
    for (int it = 0; it < NSTEP * 4; ++it) {
      const int ev = it & 3;
      const float wk = (ev == 1 || ev == 2) ? 2.f : 1.f;
      const float ce = (ev < 2) ? (DT * 0.5f) : DT;
      const bool ev0 = (ev == 0), ev3 = (ev == 3);
      const bool last = (it == NSTEP * 4 - 1);

      // pre init: subtile0 from regs, subtile1 from xkbL1
      f32x16 p0, p1;
#pragma unroll
      for (int i = 0; i < 8; ++i) {
        u32 q0 = xkbP0[i];
        u32 q1 = xkbL1[i * NTHREADS + tid];
        p0[2 * i]     = bf2f((u16)(q0 & 0xffffu));
        p0[2 * i + 1] = bf2f((u16)(q0 >> 16));
        p1[2 * i]     = bf2f((u16)(q1 & 0xffffu));
        p1[2 * i + 1] = bf2f((u16)(q1 >> 16));
      }
      // K-loop: ONE A-frag read, two B-frags (col-subtiles)
#pragma unroll 2
      for (int kb = 0; kb < 32; ++kb) {
        bf16x8 a = __builtin_bit_cast(bf16x8,
            *(const u32x4*)(heA + kb * 1024 + (aoff ^ ((kb & 7) << 4))));
        bf16x8 b0 = __builtin_bit_cast(bf16x8, Rp4[(kb * 2 + hi) * 512 + jc0]);
        bf16x8 b1 = __builtin_bit_cast(bf16x8, Rp4[(kb * 2 + hi) * 512 + jc1]);
        p0 = __builtin_amdgcn_mfma_f32_32x32x16_bf16(a, b0, p0, 0, 0, 0);
        p1 = __builtin_amdgcn_mfma_f32_32x32x16_bf16(a, b1, p1, 0, 0, 0);
      }

      // epilogue subtile0 (h in regs); stash k into p0
#pragma unroll
      for (int r = 0; r < 16; ++r) {
        int mm = (r & 3) + ((r >> 2) << 3);
        float he = bf2f(*(const u16*)(heA + cb0 + ((mm << 4) ^ U0)));
        float k = __builtin_fmaf(scl0, tanh_pre(p0[r]), -he);
        acc0[r] = ev0 ? k : __builtin_fmaf(wk, k, acc0[r]);
        if (ev3) h0[r] += (DT / 6.f) * acc0[r];
        p0[r] = k;
      }
      // epilogue subtile1 (h in h1L); stash k into p1
#pragma unroll
      for (int r = 0; r < 16; ++r) {
        int mm = (r & 3) + ((r >> 2) << 3);
        float he = bf2f(*(const u16*)(heA + cb0 + 2048 + ((mm << 4) ^ U1)));
        float k = __builtin_fmaf(scl1, tanh_pre(p1[r]), -he);
        acc1[r] = ev0 ? k : __builtin_fmaf(wk, k, acc1[r]);
        if (ev3) {
          float hv = h1L[r * NTHREADS + tid] + (DT / 6.f) * acc1[r];
          h1L[r * NTHREADS + tid] = hv;
        }
        p1[r] = k;
      }
      __syncthreads();   // all heA reads (A-frags + he_i) of this eval complete

      if (!last) {
        // write he_next = (ev3) ? h : h + ce*k  (k stashed in p0/p1)
#pragma unroll
        for (int r = 0; r < 16; ++r) {
          int mm = (r & 3) + ((r >> 2) << 3);
          float v0 = ev3 ? h0[r] : __builtin_fmaf(ce, p0[r], h0[r]);
          *(u16*)(heA + cb0 + ((mm << 4) ^ U0)) = f2bf(v0);
          float hv = h1L[r * NTHREADS + tid];
          float v1 = ev3 ? hv : __builtin_fmaf(ce, p1[r], hv);
          *(u16*)(heA + cb0 + 2048 + ((mm << 4) ^ U1)) = f2bf(v1);
        }
        __syncthreads();   // he_{i+1} visible
      }
    }
  }

  // store final h: subtile0 from regs, subtile1 from h1L
#pragma unroll
  for (int r = 0; r < 16; ++r) {
    int m = (r & 3) + ((r >> 2) << 3) + hi * 4;
    out[(r0 + m) * UNITS + jc0] = h0[r];
    out[(r0 + m) * UNITS + jc1] = h1L[r * NTHREADS + tid];
  }
}

extern "C" void kernel_launch(void* const* d_in, const int* in_sizes, int n_in,
                              void* d_out, int out_size, void* d_ws, size_t ws_size,
                              hipStream_t stream) {
  const float* X     = (const float*)d_in[0];
  const float* H0    = (const float*)d_in[1];
  const float* Km    = (const float*)d_in[2];
  const float* Rm    = (const float*)d_in[3];
  const float* bias  = (const float*)d_in[4];
  const float* scale = (const float*)d_in[5];
  float* out = (float*)d_out;

  u16* Rp = (u16*)d_ws;                  // 512*512 bf16 = 512KB
  u16* Kp = Rp + UNITS * UNITS;          // 256*512 bf16 = 256KB

  (void)hipFuncSetAttribute((const void*)ctrnn_fused,
                            hipFuncAttributeMaxDynamicSharedMemorySize, SMEM_BYTES);

  pack_weights<<<192, 256, 0, stream>>>(Km, Rm, Kp, Rp);
  ctrnn_fused<<<BATCH / BM, NTHREADS, SMEM_BYTES, stream>>>(X, H0, Kp, Rp, bias, scale, out);
}

// Round 18
// 619.119 us; speedup vs baseline: 1.1472x; 1.0103x over previous
//
#include <hip/hip_runtime.h>

typedef unsigned int u32;
typedef unsigned short u16;
typedef __bf16 bf16x8 __attribute__((ext_vector_type(8)));
typedef float f32x16 __attribute__((ext_vector_type(16)));
typedef float f32x4v __attribute__((ext_vector_type(4)));
typedef u32 u32x4 __attribute__((ext_vector_type(4)));
typedef u32 u32x2 __attribute__((ext_vector_type(2)));

#define BATCH    32768
#define DIN      256
#define UNITS    512
#define BM       32
#define NTHREADS 512
#define NSTEP    6
#define DT       (1.0f/6.0f)
#define TANH_C   2.885390082f            // 2*log2(e), folded into Kp/Rp/bias
#define SMEM_BYTES (32768 + 32768 + 16384)   // heA + h1L + xkbL1 = 80KB -> 2 blocks/CU

__device__ __forceinline__ u16 f2bf(float f) {
  return __builtin_bit_cast(u16, (__bf16)f);
}
__device__ __forceinline__ float bf2f(u16 b) {
  return __builtin_bit_cast(float, (u32)b << 16);
}
__device__ __forceinline__ u32 pk2(float a, float b) {
  return (u32)f2bf(a) | ((u32)f2bf(b) << 16);
}
// arg pre-scaled by 2*log2(e); tanh = 1 - 2/(2^t + 1). No clamp needed.
__device__ __forceinline__ float tanh_pre(float t) {
  float a = __builtin_amdgcn_exp2f(t);
  float r = __builtin_amdgcn_rcpf(a + 1.f);
  return __builtin_fmaf(-2.f, r, 1.f);
}

// Pack K (256x512) and R (512x512) f32 row-major into bf16 B-fragment order,
// PRE-SCALED by TANH_C. chunk c = g*512 + n holds rows g*8..g*8+7, col n.
__global__ void pack_weights(const float* __restrict__ Km, const float* __restrict__ Rm,
                             u16* __restrict__ Kp, u16* __restrict__ Rp) {
  int c = blockIdx.x * 256 + threadIdx.x;          // 0 .. 49151
  if (c < 32768) {
    int n = c & 511, g = c >> 9;                   // g < 64
    u32x4 p;
#pragma unroll
    for (int i = 0; i < 4; ++i) {
      u16 lo = f2bf(Rm[(g * 8 + 2 * i) * 512 + n] * TANH_C);
      u16 hh = f2bf(Rm[(g * 8 + 2 * i + 1) * 512 + n] * TANH_C);
      p[i] = (u32)lo | ((u32)hh << 16);
    }
    ((u32x4*)Rp)[c] = p;
  } else {
    int c2 = c - 32768;                            // < 16384
    int n = c2 & 511, g = c2 >> 9;                 // g < 32
    u32x4 p;
#pragma unroll
    for (int i = 0; i < 4; ++i) {
      u16 lo = f2bf(Km[(g * 8 + 2 * i) * 512 + n] * TANH_C);
      u16 hh = f2bf(Km[(g * 8 + 2 * i + 1) * 512 + n] * TANH_C);
      p[i] = (u32)lo | ((u32)hh << 16);
    }
    ((u32x4*)Kp)[c2] = p;
  }
}

__global__ __launch_bounds__(NTHREADS, 4)
void ctrnn_fused(const float* __restrict__ X, const float* __restrict__ H0,
                 const u16* __restrict__ Kp, const u16* __restrict__ Rp,
                 const float* __restrict__ bias, const float* __restrict__ scale,
                 float* __restrict__ out) {
  // heA 32KB: he bf16 [32 rows][512 cols], A-fragment order + block-XOR swizzle.
  //   addr(row,col) = (col>>4)*1024 + (((((col>>3)&1)*32+(row&31)) ^ ((col>>4)&7))<<4) + (col&7)*2
  //   A-read lane l, k-block kb: addr = kb*1024 + ((l<<4) ^ ((kb&7)<<4))  (conflict-free).
  //   he_i for a thread's own outputs lives in hevP regs — LDS copy only feeds MFMA.
  // h1L 32KB: f32 h of col-subtile1, [r][tid] per-thread-private slots.
  // xkbL1 16KB: packed-bf16 xkb of col-subtile1, u32 [i][tid].
  extern __shared__ char smem[];
  char* heA  = smem;
  float* h1L = (float*)(smem + 32768);
  u32* xkbL1 = (u32*)(smem + 65536);

  const int tid  = threadIdx.x;
  const int lane = tid & 63;
  const int wv   = tid >> 6;               // 0..7 — wave owns cols [wv*64, wv*64+64)
  const int ln   = lane & 31, hi = lane >> 5;
  const long r0  = (long)blockIdx.x * BM;

  const int jc0  = wv * 64 + ln;           // col-subtile 0
  const int jc1  = jc0 + 32;               // col-subtile 1
  const int aoff = lane << 4;
  // scalar-he write base (rows mm+hi*4, col jc0): addr = cb0 + ((mm<<4) ^ U0)
  const int chunk0 = wv * 4 + (ln >> 4);
  const int cb0 = chunk0 * 1024 + (((ln >> 3) & 1) << 9) + ((ln & 7) << 1);
  const int U0  = ((hi << 2) ^ (chunk0 & 7)) << 4;
  const int U1  = U0 ^ 32;                 // col jc1: chunk+2 -> swz^2

  // stage x tile -> swizzled A-fragment order (16 chunks, 16KB)
  {
    const f32x4v* X4 = (const f32x4v*)(X + r0 * DIN);
#pragma unroll
    for (int i = 0; i < 4; ++i) {
      int flat = i * NTHREADS + tid;       // 0..2047 float4-chunks
      int m = flat >> 6, c4 = flat & 63;   // row m (0..31), cols c4*4..+3
      f32x4v v = X4[m * 64 + c4];
      u32x2 p;
      p.x = pk2(v.x, v.y);
      p.y = pk2(v.z, v.w);
      int chunk = c4 >> 2;
      int block = ((c4 >> 1) & 1) * 32 + (m & 31);
      int addr = chunk * 1024 + ((block ^ (chunk & 7)) << 4) + (c4 & 1) * 8;
      *(u32x2*)(heA + addr) = p;
    }
  }

  const float scl0 = scale[jc0], scl1 = scale[jc1];

  // load h: col-subtile0 -> regs, col-subtile1 -> h1L
  float h0[16];
#pragma unroll
  for (int r = 0; r < 16; ++r) {
    int m = (r & 3) + ((r >> 2) << 3) + hi * 4;
    h0[r] = H0[(r0 + m) * UNITS + jc0];
    h1L[r * NTHREADS + tid] = H0[(r0 + m) * UNITS + jc1];
  }

  __syncthreads();

  // ---- prologue: xkb = TANH_C*(x@K + b) ----
  u32 hevP0[8], hevP1[8];                  // packed bf16 he_i of own outputs
  {
    f32x16 pre0, pre1;
    {
      float b0 = bias[jc0] * TANH_C, b1 = bias[jc1] * TANH_C;
#pragma unroll
      for (int r = 0; r < 16; ++r) { pre0[r] = b0; pre1[r] = b1; }
    }
    const u32x4* Kp4 = (const u32x4*)Kp;
#pragma unroll 2
    for (int kb = 0; kb < 16; ++kb) {
      bf16x8 a = __builtin_bit_cast(bf16x8,
          *(const u32x4*)(heA + kb * 1024 + (aoff ^ ((kb & 7) << 4))));
      bf16x8 b0 = __builtin_bit_cast(bf16x8, Kp4[(kb * 2 + hi) * 512 + jc0]);
      bf16x8 b1 = __builtin_bit_cast(bf16x8, Kp4[(kb * 2 + hi) * 512 + jc1]);
      pre0 = __builtin_amdgcn_mfma_f32_32x32x16_bf16(a, b0, pre0, 0, 0, 0);
      pre1 = __builtin_amdgcn_mfma_f32_32x32x16_bf16(a, b1, pre1, 0, 0, 0);
    }
    u32 xkbP0t[8];
#pragma unroll
    for (int i = 0; i < 8; ++i) {
      xkbP0t[i] = pk2(pre0[2 * i], pre0[2 * i + 1]);
      xkbL1[i * NTHREADS + tid] = pk2(pre1[2 * i], pre1[2 * i + 1]);
    }
    __syncthreads();   // prologue x-reads + xkbL1 writes complete; heA -> he buffer

    // he_1 = bf16(h): pack to regs, store same bits to LDS
#pragma unroll
    for (int rp = 0; rp < 8; ++rp) {
      hevP0[rp] = pk2(h0[2 * rp], h0[2 * rp + 1]);
      hevP1[rp] = pk2(h1L[(2 * rp) * NTHREADS + tid], h1L[(2 * rp + 1) * NTHREADS + tid]);
#pragma unroll
      for (int half = 0; half < 2; ++half) {
        int r = 2 * rp + half;
        int mm = (r & 3) + ((r >> 2) << 3);
        *(u16*)(heA + cb0 + ((mm << 4) ^ U0)) =
            (u16)(half ? (hevP0[rp] >> 16) : (hevP0[rp] & 0xffffu));
        *(u16*)(heA + cb0 + 2048 + ((mm << 4) ^ U1)) =
            (u16)(half ? (hevP1[rp] >> 16) : (hevP1[rp] & 0xffffu));
      }
    }
    __syncthreads();

    const u32x4* Rp4 = (const u32x4*)Rp;
    float acc0[16], acc1[16];
    u32 xkbP0[8];
#pragma unroll
    for (int i = 0; i < 8; ++i) xkbP0[i] = xkbP0t[i];

#pragma unroll 1
    for (int it = 0; it < NSTEP * 4; ++it) {
      const int ev = it & 3;
      const float wk = (ev == 1 || ev == 2) ? 2.f : 1.f;
      const float ce = (ev < 2) ? (DT * 0.5f) : DT;
      const bool ev0 = (ev == 0), ev3 = (ev == 3);
      const bool last = (it == NSTEP * 4 - 1);

      // pre init: subtile0 from regs, subtile1 from xkbL1
      f32x16 p0, p1;
#pragma unroll
      for (int i = 0; i < 8; ++i) {
        u32 q0 = xkbP0[i];
        u32 q1 = xkbL1[i * NTHREADS + tid];
        p0[2 * i]     = bf2f((u16)(q0 & 0xffffu));
        p0[2 * i + 1] = bf2f((u16)(q0 >> 16));
        p1[2 * i]     = bf2f((u16)(q1 & 0xffffu));
        p1[2 * i + 1] = bf2f((u16)(q1 >> 16));
      }
      // K-loop: ONE A-frag read, two B-frags (col-subtiles)
#pragma unroll 2
      for (int kb = 0; kb < 32; ++kb) {
        bf16x8 a = __builtin_bit_cast(bf16x8,
            *(const u32x4*)(heA + kb * 1024 + (aoff ^ ((kb & 7) << 4))));
        bf16x8 b0 = __builtin_bit_cast(bf16x8, Rp4[(kb * 2 + hi) * 512 + jc0]);
        bf16x8 b1 = __builtin_bit_cast(bf16x8, Rp4[(kb * 2 + hi) * 512 + jc1]);
        p0 = __builtin_amdgcn_mfma_f32_32x32x16_bf16(a, b0, p0, 0, 0, 0);
        p1 = __builtin_amdgcn_mfma_f32_32x32x16_bf16(a, b1, p1, 0, 0, 0);
      }

      // epilogue: he_i from hevP regs (no LDS read); stash k into p0/p1
#pragma unroll
      for (int rp = 0; rp < 8; ++rp) {
#pragma unroll
        for (int half = 0; half < 2; ++half) {
          int r = 2 * rp + half;
          float he0 = bf2f((u16)(half ? (hevP0[rp] >> 16) : (hevP0[rp] & 0xffffu)));
          float he1 = bf2f((u16)(half ? (hevP1[rp] >> 16) : (hevP1[rp] & 0xffffu)));
          float k0 = __builtin_fmaf(scl0, tanh_pre(p0[r]), -he0);
          float k1 = __builtin_fmaf(scl1, tanh_pre(p1[r]), -he1);
          acc0[r] = ev0 ? k0 : __builtin_fmaf(wk, k0, acc0[r]);
          acc1[r] = ev0 ? k1 : __builtin_fmaf(wk, k1, acc1[r]);
          if (ev3) {
            h0[r] += (DT / 6.f) * acc0[r];
            h1L[r * NTHREADS + tid] += (DT / 6.f) * acc1[r];
          }
          p0[r] = k0; p1[r] = k1;
        }
      }
      __syncthreads();   // all heA A-frag reads of this eval complete

      if (!last) {
        // he_next = (ev3) ? h : h + ce*k ; pack to hevP, store same bits to LDS
#pragma unroll
        for (int rp = 0; rp < 8; ++rp) {
          float v0a, v0b, v1a, v1b;
          if (ev3) {
            v0a = h0[2 * rp]; v0b = h0[2 * rp + 1];
            v1a = h1L[(2 * rp) * NTHREADS + tid];
            v1b = h1L[(2 * rp + 1) * NTHREADS + tid];
          } else {
            v0a = __builtin_fmaf(ce, p0[2 * rp],     h0[2 * rp]);
            v0b = __builtin_fmaf(ce, p0[2 * rp + 1], h0[2 * rp + 1]);
            v1a = __builtin_fmaf(ce, p1[2 * rp],     h1L[(2 * rp) * NTHREADS + tid]);
            v1b = __builtin_fmaf(ce, p1[2 * rp + 1], h1L[(2 * rp + 1) * NTHREADS + tid]);
          }
          hevP0[rp] = pk2(v0a, v0b);
          hevP1[rp] = pk2(v1a, v1b);
#pragma unroll
          for (int half = 0; half < 2; ++half) {
            int r = 2 * rp + half;
            int mm = (r & 3) + ((r >> 2) << 3);
            *(u16*)(heA + cb0 + ((mm << 4) ^ U0)) =
                (u16)(half ? (hevP0[rp] >> 16) : (hevP0[rp] & 0xffffu));
            *(u16*)(heA + cb0 + 2048 + ((mm << 4) ^ U1)) =
                (u16)(half ? (hevP1[rp] >> 16) : (hevP1[rp] & 0xffffu));
          }
        }
        __syncthreads();   // he_{i+1} visible
      }
    }
  }

  // store final h: subtile0 from regs, subtile1 from h1L
#pragma unroll
  for (int r = 0; r < 16; ++r) {
    int m = (r & 3) + ((r >> 2) << 3) + hi * 4;
    out[(r0 + m) * UNITS + jc0] = h0[r];
    out[(r0 + m) * UNITS + jc1] = h1L[r * NTHREADS + tid];
  }
}

extern "C" void kernel_launch(void* const* d_in, const int* in_sizes, int n_in,
                              void* d_out, int out_size, void* d_ws, size_t ws_size,
                              hipStream_t stream) {
  const float* X     = (const float*)d_in[0];
  const float* H0    = (const float*)d_in[1];
  const float* Km    = (const float*)d_in[2];
  const float* Rm    = (const float*)d_in[3];
  const float* bias  = (const float*)d_in[4];
  const float* scale = (const float*)d_in[5];
  float* out = (float*)d_out;

  u16* Rp = (u16*)d_ws;                  // 512*512 bf16 = 512KB
  u16* Kp = Rp + UNITS * UNITS;          // 256*512 bf16 = 256KB

  (void)hipFuncSetAttribute((const void*)ctrnn_fused,
                            hipFuncAttributeMaxDynamicSharedMemorySize, SMEM_BYTES);

  pack_weights<<<192, 256, 0, stream>>>(Km, Rm, Kp, Rp);
  ctrnn_fused<<<BATCH / BM, NTHREADS, SMEM_BYTES, stream>>>(X, H0, Kp, Rp, bias, scale, out);
}